// Round 1
// baseline (173.819 us; speedup 1.0000x reference)
//
#include <hip/hip_runtime.h>
#include <math.h>

// ---------------------------------------------------------------------------
// QCPINN: pre-MLP(1->32->32->2, tanh) -> 2-qubit circuit -> post-MLP(2->32->32->1)
// N = 1e6 samples. Entirely compute-bound (8 MB total HBM traffic).
//
// The trainable circuit (2 layers of RZ·RY·RX per wire + CNOT) is sample-
// independent -> collapse it to one fixed 4x4 complex matrix U, computed by a
// 1-thread setup kernel into d_ws. Per sample the quantum block is then:
//   e = [c0c1, c0s1, s0c1, s0s1] (real),  v = U e,  p_m = |v_m|^2,
//   z0 = p0+p1-p2-p3, z1 = p0-p1+p2-p3.
// ---------------------------------------------------------------------------

struct cplx { float re, im; };
__device__ __forceinline__ cplx cmul(cplx a, cplx b) {
    return { a.re * b.re - a.im * b.im, a.re * b.im + a.im * b.re };
}
__device__ __forceinline__ cplx cadd(cplx a, cplx b) {
    return { a.re + b.re, a.im + b.im };
}

// Computes U = L1 * L0, where Ll = P_cnot * (I (x) g1) * (g0 (x) I),
// g = RZ(c)·RY(b)·RX(a). Stores ws[0..15]=Re(U), ws[16..31]=Im(U).
__global__ void qcpinn_setup_kernel(const float* __restrict__ qw,
                                    float* __restrict__ ws) {
    if (threadIdx.x != 0 || blockIdx.x != 0) return;

    cplx U[16];
    for (int i = 0; i < 16; ++i) U[i] = {0.f, 0.f};
    U[0].re = U[5].re = U[10].re = U[15].re = 1.f;

    for (int l = 0; l < 2; ++l) {
        cplx g[2][4];
        for (int w = 0; w < 2; ++w) {
            float a = qw[l * 6 + w * 3 + 0];
            float b = qw[l * 6 + w * 3 + 1];
            float c = qw[l * 6 + w * 3 + 2];
            float ca = cosf(0.5f * a), sa = sinf(0.5f * a);
            float cb = cosf(0.5f * b), sb = sinf(0.5f * b);
            float cc = cosf(0.5f * c), sc = sinf(0.5f * c);
            cplx RX[4] = {{ca, 0.f}, {0.f, -sa}, {0.f, -sa}, {ca, 0.f}};
            cplx RY[4] = {{cb, 0.f}, {-sb, 0.f}, {sb, 0.f}, {cb, 0.f}};
            cplx RZ[4] = {{cc, -sc}, {0.f, 0.f}, {0.f, 0.f}, {cc, sc}};
            cplx T[4];
            for (int i2 = 0; i2 < 2; ++i2)
                for (int j2 = 0; j2 < 2; ++j2) {
                    cplx s_ = {0.f, 0.f};
                    for (int k2 = 0; k2 < 2; ++k2)
                        s_ = cadd(s_, cmul(RY[i2 * 2 + k2], RX[k2 * 2 + j2]));
                    T[i2 * 2 + j2] = s_;
                }
            for (int i2 = 0; i2 < 2; ++i2)
                for (int j2 = 0; j2 < 2; ++j2) {
                    cplx s_ = {0.f, 0.f};
                    for (int k2 = 0; k2 < 2; ++k2)
                        s_ = cadd(s_, cmul(RZ[i2 * 2 + k2], T[k2 * 2 + j2]));
                    g[w][i2 * 2 + j2] = s_;
                }
        }
        // A = g0 (x) I, B = I (x) g1  (vec index m = 2*q0 + q1)
        cplx A[16], B[16], T4[16], L[16];
        for (int a2 = 0; a2 < 2; ++a2)
            for (int b2 = 0; b2 < 2; ++b2)
                for (int c2 = 0; c2 < 2; ++c2)
                    for (int d2 = 0; d2 < 2; ++d2) {
                        A[(a2 * 2 + b2) * 4 + (c2 * 2 + d2)] =
                            (b2 == d2) ? g[0][a2 * 2 + c2] : cplx{0.f, 0.f};
                        B[(a2 * 2 + b2) * 4 + (c2 * 2 + d2)] =
                            (a2 == c2) ? g[1][b2 * 2 + d2] : cplx{0.f, 0.f};
                    }
        for (int i4 = 0; i4 < 4; ++i4)
            for (int j4 = 0; j4 < 4; ++j4) {
                cplx s_ = {0.f, 0.f};
                for (int k4 = 0; k4 < 4; ++k4)
                    s_ = cadd(s_, cmul(B[i4 * 4 + k4], A[k4 * 4 + j4]));
                T4[i4 * 4 + j4] = s_;
            }
        // CNOT: swap rows 2 and 3
        for (int j4 = 0; j4 < 4; ++j4) {
            L[0 * 4 + j4] = T4[0 * 4 + j4];
            L[1 * 4 + j4] = T4[1 * 4 + j4];
            L[2 * 4 + j4] = T4[3 * 4 + j4];
            L[3 * 4 + j4] = T4[2 * 4 + j4];
        }
        cplx Un[16];
        for (int i4 = 0; i4 < 4; ++i4)
            for (int j4 = 0; j4 < 4; ++j4) {
                cplx s_ = {0.f, 0.f};
                for (int k4 = 0; k4 < 4; ++k4)
                    s_ = cadd(s_, cmul(L[i4 * 4 + k4], U[k4 * 4 + j4]));
                Un[i4 * 4 + j4] = s_;
            }
        for (int i = 0; i < 16; ++i) U[i] = Un[i];
    }
    for (int i = 0; i < 16; ++i) { ws[i] = U[i].re; ws[16 + i] = U[i].im; }
}

// tanh(x) = 1 - 2/(exp(2x)+1); saturates correctly at +-inf.
__device__ __forceinline__ float fast_tanh(float x) {
    float e = __expf(2.0f * x);
    return fmaf(-2.0f, __builtin_amdgcn_rcpf(e + 1.0f), 1.0f);
}

__global__ __launch_bounds__(256) void qcpinn_kernel(
    const float* __restrict__ x,
    const float* __restrict__ pw1, const float* __restrict__ pb1,
    const float* __restrict__ pw2, const float* __restrict__ pb2,
    const float* __restrict__ pw3, const float* __restrict__ pb3,
    const float* __restrict__ U,
    const float* __restrict__ ow1, const float* __restrict__ ob1,
    const float* __restrict__ ow2, const float* __restrict__ ob2,
    const float* __restrict__ ow3, const float* __restrict__ ob3,
    float* __restrict__ out, int N)
{
    int i = blockIdx.x * blockDim.x + threadIdx.x;
    if (i >= N) return;

    float xv = x[i];
    float h1[32], h2[32];

    // pre layer 1: 1 -> 32
    #pragma unroll
    for (int j = 0; j < 32; ++j)
        h1[j] = fast_tanh(fmaf(xv, pw1[j], pb1[j]));

    // pre layer 2: 32 -> 32  (weights are wave-uniform -> s_load scalar operands)
    #pragma unroll
    for (int j = 0; j < 32; ++j) {
        float a = pb2[j];
        #pragma unroll
        for (int k = 0; k < 32; ++k)
            a = fmaf(h1[k], pw2[k * 32 + j], a);
        h2[j] = fast_tanh(a);
    }

    // pre layer 3: 32 -> 2
    float q0 = pb3[0], q1 = pb3[1];
    #pragma unroll
    for (int k = 0; k < 32; ++k) {
        q0 = fmaf(h2[k], pw3[k * 2 + 0], q0);
        q1 = fmaf(h2[k], pw3[k * 2 + 1], q1);
    }

    // quantum block: encoding is real rank-1 vector; circuit is fixed U.
    float s0, c0, s1, c1;
    __sincosf(0.5f * q0, &s0, &c0);
    __sincosf(0.5f * q1, &s1, &c1);
    float e0 = c0 * c1, e1 = c0 * s1, e2 = s0 * c1, e3 = s0 * s1;

    float p[4];
    #pragma unroll
    for (int m = 0; m < 4; ++m) {
        float re = fmaf(U[m * 4 + 0], e0,
                   fmaf(U[m * 4 + 1], e1,
                   fmaf(U[m * 4 + 2], e2, U[m * 4 + 3] * e3)));
        float im = fmaf(U[16 + m * 4 + 0], e0,
                   fmaf(U[16 + m * 4 + 1], e1,
                   fmaf(U[16 + m * 4 + 2], e2, U[16 + m * 4 + 3] * e3)));
        p[m] = fmaf(re, re, im * im);
    }
    float z0 = p[0] + p[1] - p[2] - p[3];
    float z1 = p[0] - p[1] + p[2] - p[3];

    // post layer 1: 2 -> 32
    #pragma unroll
    for (int j = 0; j < 32; ++j)
        h1[j] = fast_tanh(fmaf(z0, ow1[j], fmaf(z1, ow1[32 + j], ob1[j])));

    // post layer 2: 32 -> 32
    #pragma unroll
    for (int j = 0; j < 32; ++j) {
        float a = ob2[j];
        #pragma unroll
        for (int k = 0; k < 32; ++k)
            a = fmaf(h1[k], ow2[k * 32 + j], a);
        h2[j] = fast_tanh(a);
    }

    // post layer 3: 32 -> 1
    float u = ob3[0];
    #pragma unroll
    for (int k = 0; k < 32; ++k)
        u = fmaf(h2[k], ow3[k], u);

    out[i] = u;
}

extern "C" void kernel_launch(void* const* d_in, const int* in_sizes, int n_in,
                              void* d_out, int out_size, void* d_ws, size_t ws_size,
                              hipStream_t stream) {
    const float* x   = (const float*)d_in[0];
    const float* pw1 = (const float*)d_in[1];
    const float* pb1 = (const float*)d_in[2];
    const float* pw2 = (const float*)d_in[3];
    const float* pb2 = (const float*)d_in[4];
    const float* pw3 = (const float*)d_in[5];
    const float* pb3 = (const float*)d_in[6];
    const float* qw  = (const float*)d_in[7];
    const float* ow1 = (const float*)d_in[8];
    const float* ob1 = (const float*)d_in[9];
    const float* ow2 = (const float*)d_in[10];
    const float* ob2 = (const float*)d_in[11];
    const float* ow3 = (const float*)d_in[12];
    const float* ob3 = (const float*)d_in[13];
    float* out = (float*)d_out;
    float* ws  = (float*)d_ws;   // ws[0..31] = U (re[16], im[16])

    const int N = in_sizes[0];

    qcpinn_setup_kernel<<<1, 64, 0, stream>>>(qw, ws);

    const int block = 256;
    const int grid  = (N + block - 1) / block;
    qcpinn_kernel<<<grid, block, 0, stream>>>(
        x, pw1, pb1, pw2, pb2, pw3, pb3, ws,
        ow1, ob1, ow2, ob2, ow3, ob3, out, N);
}

// Round 2
// 130.275 us; speedup vs baseline: 1.3342x; 1.3342x over previous
//
#include <hip/hip_runtime.h>
#include <math.h>
#include <stdint.h>

// ---------------------------------------------------------------------------
// QCPINN via MFMA: pre-MLP(1->32->32->2) -> fixed 4x4 complex circuit U ->
// post-MLP(2->32->32->1), N=1e6.
//
// Wave layout: 64 lanes = 4 groups (g=lane>>4) x 16 samples (s=lane&15).
// Each wave handles 2 tiles of 16 samples (32 samples/wave).
// 32x32 layers: C = W^T x H^T via v_mfma_f32_16x16x32_bf16 with hi/lo bf16
// split (3 MFMA passes) for ~fp32 accuracy.
//   B-frag (H^T): lane holds h[sample=lane&15][k=(lane>>4)*8+j], j=0..7
//   A-frag (W^T): lane holds W[k=(lane>>4)*8+j][out=r*16+(lane&15)]  (packed
//                 by setup kernel into d_ws)
//   C-frag:       lane holds C[out=(lane>>4)*4+i (+16 for tile2)][sample=lane&15]
// The 32->2 / 32->1 layers are per-lane partial dots on the C-frag + shfl_xor
// butterfly over lanes {s, s+16, s+32, s+48}. No LDS needed anywhere.
// ---------------------------------------------------------------------------

typedef __attribute__((ext_vector_type(8))) short short8;   // 8 x bf16
typedef __attribute__((ext_vector_type(4))) float f32x4;

union Frag { uint32_t u[4]; short8 s; };

__device__ __forceinline__ float fast_tanh(float x) {
    float e = __expf(2.0f * x);
    return fmaf(-2.0f, __builtin_amdgcn_rcpf(e + 1.0f), 1.0f);
}

// split 8 f32 -> packed bf16 hi (4 uints) + lo (4 uints); truncation split,
// combined precision ~2^-17 relative.
__device__ __forceinline__ void split8(const float h[8], uint32_t hi[4], uint32_t lo[4]) {
    #pragma unroll
    for (int p = 0; p < 4; ++p) {
        uint32_t u0 = __float_as_uint(h[2*p])   & 0xFFFF0000u;
        uint32_t u1 = __float_as_uint(h[2*p+1]) & 0xFFFF0000u;
        float l0 = h[2*p]   - __uint_as_float(u0);
        float l1 = h[2*p+1] - __uint_as_float(u1);
        uint32_t v0 = __float_as_uint(l0) & 0xFFFF0000u;
        uint32_t v1 = __float_as_uint(l1) & 0xFFFF0000u;
        hi[p] = (u0 >> 16) | u1;   // elem 2p in low short, 2p+1 in high short
        lo[p] = (v0 >> 16) | v1;
    }
}

struct cplx { float re, im; };
__device__ __forceinline__ cplx cmul(cplx a, cplx b) {
    return { a.re * b.re - a.im * b.im, a.re * b.im + a.im * b.re };
}
__device__ __forceinline__ cplx cadd(cplx a, cplx b) {
    return { a.re + b.re, a.im + b.im };
}

// ---------------------------------------------------------------------------
// Setup: (a) all 64 lanes pack W2/OW2 into A-frag hi/lo order in ws;
//        (b) lane 0 computes the fixed 4x4 circuit matrix U (fast __sincosf).
// ws layout (uint32 units): [0..31] U floats (re16, im16);
//   [32 + (kind*64 + lane)*4 ..] frags, kind = mat*4 + r*2 + (0 hi | 1 lo),
//   mat 0 = pre_w2, mat 1 = post_w2.  Total 32 + 2048 uints = 8.3 KB.
// ---------------------------------------------------------------------------
__global__ void qcpinn_setup(const float* __restrict__ qw,
                             const float* __restrict__ pw2,
                             const float* __restrict__ ow2,
                             float* __restrict__ ws) {
    const int lane = threadIdx.x & 63;
    const int s = lane & 15, gg = lane >> 4;
    uint32_t* wsu = (uint32_t*)ws;

    #pragma unroll
    for (int m = 0; m < 2; ++m) {
        const float* W = m ? ow2 : pw2;   // [32 in][32 out] row-major
        #pragma unroll
        for (int r = 0; r < 2; ++r) {
            float v[8];
            #pragma unroll
            for (int j = 0; j < 8; ++j)
                v[j] = W[(gg * 8 + j) * 32 + (r * 16 + s)];
            uint32_t hi[4], lo[4];
            split8(v, hi, lo);
            int bh = 32 + ((m * 4 + r * 2 + 0) * 64 + lane) * 4;
            int bl = 32 + ((m * 4 + r * 2 + 1) * 64 + lane) * 4;
            #pragma unroll
            for (int p = 0; p < 4; ++p) { wsu[bh + p] = hi[p]; wsu[bl + p] = lo[p]; }
        }
    }

    if (threadIdx.x == 0) {
        cplx U[16];
        for (int i = 0; i < 16; ++i) U[i] = {0.f, 0.f};
        U[0].re = U[5].re = U[10].re = U[15].re = 1.f;

        for (int l = 0; l < 2; ++l) {
            cplx g[2][4];
            for (int w = 0; w < 2; ++w) {
                float a = qw[l * 6 + w * 3 + 0];
                float b = qw[l * 6 + w * 3 + 1];
                float c = qw[l * 6 + w * 3 + 2];
                float sa, ca, sb, cb, sc, cc;
                __sincosf(0.5f * a, &sa, &ca);
                __sincosf(0.5f * b, &sb, &cb);
                __sincosf(0.5f * c, &sc, &cc);
                cplx RX[4] = {{ca, 0.f}, {0.f, -sa}, {0.f, -sa}, {ca, 0.f}};
                cplx RY[4] = {{cb, 0.f}, {-sb, 0.f}, {sb, 0.f}, {cb, 0.f}};
                cplx RZ[4] = {{cc, -sc}, {0.f, 0.f}, {0.f, 0.f}, {cc, sc}};
                cplx T[4];
                for (int i2 = 0; i2 < 2; ++i2)
                    for (int j2 = 0; j2 < 2; ++j2) {
                        cplx acc = {0.f, 0.f};
                        for (int k2 = 0; k2 < 2; ++k2)
                            acc = cadd(acc, cmul(RY[i2 * 2 + k2], RX[k2 * 2 + j2]));
                        T[i2 * 2 + j2] = acc;
                    }
                for (int i2 = 0; i2 < 2; ++i2)
                    for (int j2 = 0; j2 < 2; ++j2) {
                        cplx acc = {0.f, 0.f};
                        for (int k2 = 0; k2 < 2; ++k2)
                            acc = cadd(acc, cmul(RZ[i2 * 2 + k2], T[k2 * 2 + j2]));
                        g[w][i2 * 2 + j2] = acc;
                    }
            }
            // M[i][j] = g1[i&1][j&1] * g0[i>>1][j>>1]; CNOT swaps rows 2,3; U = L*U
            cplx L[16];
            for (int i4 = 0; i4 < 4; ++i4) {
                int si = (i4 == 2) ? 3 : (i4 == 3) ? 2 : i4;
                for (int j4 = 0; j4 < 4; ++j4)
                    L[i4 * 4 + j4] = cmul(g[1][(si & 1) * 2 + (j4 & 1)],
                                          g[0][(si >> 1) * 2 + (j4 >> 1)]);
            }
            cplx Un[16];
            for (int i4 = 0; i4 < 4; ++i4)
                for (int j4 = 0; j4 < 4; ++j4) {
                    cplx acc = {0.f, 0.f};
                    for (int k4 = 0; k4 < 4; ++k4)
                        acc = cadd(acc, cmul(L[i4 * 4 + k4], U[k4 * 4 + j4]));
                    Un[i4 * 4 + j4] = acc;
                }
            for (int i = 0; i < 16; ++i) U[i] = Un[i];
        }
        for (int i = 0; i < 16; ++i) { ws[i] = U[i].re; ws[16 + i] = U[i].im; }
    }
}

// ---------------------------------------------------------------------------
// Main kernel: block = 128 threads = 2 waves; each wave = 2 tiles x 16 samples.
// Grid = ceil(N/64).
// ---------------------------------------------------------------------------
__global__ __launch_bounds__(128) void qcpinn_main(
    const float* __restrict__ x,
    const float* __restrict__ pw1, const float* __restrict__ pb1,
    const float* __restrict__ pb2, const float* __restrict__ pw3,
    const float* __restrict__ pb3,
    const float* __restrict__ ws,
    const float* __restrict__ ow1, const float* __restrict__ ob1,
    const float* __restrict__ ob2, const float* __restrict__ ow3,
    const float* __restrict__ ob3,
    float* __restrict__ out, int N)
{
    const int lane = threadIdx.x & 63;
    const int wid  = threadIdx.x >> 6;
    const int s    = lane & 15;
    const int g    = lane >> 4;
    const int wave_id = blockIdx.x * 2 + wid;

    int samp[2];
    samp[0] = wave_id * 32 + s;
    samp[1] = samp[0] + 16;

    const float* U = ws;                           // uniform, const-indexed -> s_load
    const Frag* fragp = (const Frag*)(ws + 32);    // [kind*64 + lane]

    // ---------------- pre layer 1: 1 -> 32 (produces B-frag directly) -------
    float xv[2];
    xv[0] = (samp[0] < N) ? x[samp[0]] : 0.f;
    xv[1] = (samp[1] < N) ? x[samp[1]] : 0.f;

    f32x4 w1a = *(const f32x4*)(pw1 + g * 8);
    f32x4 w1b = *(const f32x4*)(pw1 + g * 8 + 4);
    f32x4 b1a = *(const f32x4*)(pb1 + g * 8);
    f32x4 b1b = *(const f32x4*)(pb1 + g * 8 + 4);

    Frag Bh[2], Bl[2];
    #pragma unroll
    for (int t = 0; t < 2; ++t) {
        float h[8];
        #pragma unroll
        for (int j = 0; j < 4; ++j) {
            h[j]     = fast_tanh(fmaf(xv[t], w1a[j], b1a[j]));
            h[4 + j] = fast_tanh(fmaf(xv[t], w1b[j], b1b[j]));
        }
        split8(h, Bh[t].u, Bl[t].u);
    }

    // ---------------- pre layer 2: 32 -> 32 via MFMA ------------------------
    Frag A0h = fragp[0 * 64 + lane];
    Frag A0l = fragp[1 * 64 + lane];
    Frag A1h = fragp[2 * 64 + lane];
    Frag A1l = fragp[3 * 64 + lane];

    f32x4 pb2a = *(const f32x4*)(pb2 + g * 4);
    f32x4 pb2b = *(const f32x4*)(pb2 + 16 + g * 4);

    float h2[2][8];   // [tile][i: feats g*4+i (0..3), 16+g*4+i (4..7)] of sample s
    #pragma unroll
    for (int t = 0; t < 2; ++t) {
        f32x4 C0 = {0.f, 0.f, 0.f, 0.f};
        f32x4 C1 = {0.f, 0.f, 0.f, 0.f};
        C0 = __builtin_amdgcn_mfma_f32_16x16x32_bf16(A0h.s, Bh[t].s, C0, 0, 0, 0);
        C0 = __builtin_amdgcn_mfma_f32_16x16x32_bf16(A0h.s, Bl[t].s, C0, 0, 0, 0);
        C0 = __builtin_amdgcn_mfma_f32_16x16x32_bf16(A0l.s, Bh[t].s, C0, 0, 0, 0);
        C1 = __builtin_amdgcn_mfma_f32_16x16x32_bf16(A1h.s, Bh[t].s, C1, 0, 0, 0);
        C1 = __builtin_amdgcn_mfma_f32_16x16x32_bf16(A1h.s, Bl[t].s, C1, 0, 0, 0);
        C1 = __builtin_amdgcn_mfma_f32_16x16x32_bf16(A1l.s, Bh[t].s, C1, 0, 0, 0);
        #pragma unroll
        for (int i = 0; i < 4; ++i) {
            h2[t][i]     = fast_tanh(C0[i] + pb2a[i]);
            h2[t][4 + i] = fast_tanh(C1[i] + pb2b[i]);
        }
    }

    // ---------------- pre layer 3 (32->2) + quantum -------------------------
    // pw3 is [32][2] row-major; lane holds rows {g*4+i, 16+g*4+i}.
    f32x4 w3a = *(const f32x4*)(pw3 + g * 8);            // rows g*4, g*4+1
    f32x4 w3b = *(const f32x4*)(pw3 + g * 8 + 4);        // rows g*4+2, g*4+3
    f32x4 w3c = *(const f32x4*)(pw3 + 32 + g * 8);       // rows 16+g*4, +1
    f32x4 w3d = *(const f32x4*)(pw3 + 32 + g * 8 + 4);   // rows 16+g*4+2, +3
    float bq0 = pb3[0], bq1 = pb3[1];

    float z0[2], z1[2];
    #pragma unroll
    for (int t = 0; t < 2; ++t) {
        float q0 = 0.f, q1 = 0.f;
        q0 = fmaf(h2[t][0], w3a[0], q0); q1 = fmaf(h2[t][0], w3a[1], q1);
        q0 = fmaf(h2[t][1], w3a[2], q0); q1 = fmaf(h2[t][1], w3a[3], q1);
        q0 = fmaf(h2[t][2], w3b[0], q0); q1 = fmaf(h2[t][2], w3b[1], q1);
        q0 = fmaf(h2[t][3], w3b[2], q0); q1 = fmaf(h2[t][3], w3b[3], q1);
        q0 = fmaf(h2[t][4], w3c[0], q0); q1 = fmaf(h2[t][4], w3c[1], q1);
        q0 = fmaf(h2[t][5], w3c[2], q0); q1 = fmaf(h2[t][5], w3c[3], q1);
        q0 = fmaf(h2[t][6], w3d[0], q0); q1 = fmaf(h2[t][6], w3d[1], q1);
        q0 = fmaf(h2[t][7], w3d[2], q0); q1 = fmaf(h2[t][7], w3d[3], q1);
        // butterfly over lanes {s, s+16, s+32, s+48}
        q0 += __shfl_xor(q0, 16); q0 += __shfl_xor(q0, 32);
        q1 += __shfl_xor(q1, 16); q1 += __shfl_xor(q1, 32);
        q0 += bq0; q1 += bq1;

        float s0, c0, s1, c1;
        __sincosf(0.5f * q0, &s0, &c0);
        __sincosf(0.5f * q1, &s1, &c1);
        float e0 = c0 * c1, e1 = c0 * s1, e2 = s0 * c1, e3 = s0 * s1;
        float p[4];
        #pragma unroll
        for (int m = 0; m < 4; ++m) {
            float re = fmaf(U[m * 4 + 0], e0, fmaf(U[m * 4 + 1], e1,
                       fmaf(U[m * 4 + 2], e2, U[m * 4 + 3] * e3)));
            float im = fmaf(U[16 + m * 4 + 0], e0, fmaf(U[16 + m * 4 + 1], e1,
                       fmaf(U[16 + m * 4 + 2], e2, U[16 + m * 4 + 3] * e3)));
            p[m] = fmaf(re, re, im * im);
        }
        z0[t] = p[0] + p[1] - p[2] - p[3];
        z1[t] = p[0] - p[1] + p[2] - p[3];
    }

    // ---------------- post layer 1: 2 -> 32 (B-frag directly) ---------------
    f32x4 oa  = *(const f32x4*)(ow1 + g * 8);            // ow1[0][g*8..]
    f32x4 oa2 = *(const f32x4*)(ow1 + g * 8 + 4);
    f32x4 ob  = *(const f32x4*)(ow1 + 32 + g * 8);       // ow1[1][g*8..]
    f32x4 ob2v= *(const f32x4*)(ow1 + 32 + g * 8 + 4);
    f32x4 obb = *(const f32x4*)(ob1 + g * 8);
    f32x4 obb2= *(const f32x4*)(ob1 + g * 8 + 4);

    Frag B2h[2], B2l[2];
    #pragma unroll
    for (int t = 0; t < 2; ++t) {
        float h[8];
        #pragma unroll
        for (int j = 0; j < 4; ++j) {
            h[j]     = fast_tanh(fmaf(z0[t], oa[j],  fmaf(z1[t], ob[j],   obb[j])));
            h[4 + j] = fast_tanh(fmaf(z0[t], oa2[j], fmaf(z1[t], ob2v[j], obb2[j])));
        }
        split8(h, B2h[t].u, B2l[t].u);
    }

    // ---------------- post layer 2: 32 -> 32 via MFMA -----------------------
    Frag P0h = fragp[4 * 64 + lane];
    Frag P0l = fragp[5 * 64 + lane];
    Frag P1h = fragp[6 * 64 + lane];
    Frag P1l = fragp[7 * 64 + lane];

    f32x4 ob2a = *(const f32x4*)(ob2 + g * 4);
    f32x4 ob2b = *(const f32x4*)(ob2 + 16 + g * 4);

    // ---------------- post layer 3: 32 -> 1 + store -------------------------
    f32x4 w3o0 = *(const f32x4*)(ow3 + g * 4);           // rows g*4..+3
    f32x4 w3o1 = *(const f32x4*)(ow3 + 16 + g * 4);      // rows 16+g*4..+3
    float bo = ob3[0];

    #pragma unroll
    for (int t = 0; t < 2; ++t) {
        f32x4 C0 = {0.f, 0.f, 0.f, 0.f};
        f32x4 C1 = {0.f, 0.f, 0.f, 0.f};
        C0 = __builtin_amdgcn_mfma_f32_16x16x32_bf16(P0h.s, B2h[t].s, C0, 0, 0, 0);
        C0 = __builtin_amdgcn_mfma_f32_16x16x32_bf16(P0h.s, B2l[t].s, C0, 0, 0, 0);
        C0 = __builtin_amdgcn_mfma_f32_16x16x32_bf16(P0l.s, B2h[t].s, C0, 0, 0, 0);
        C1 = __builtin_amdgcn_mfma_f32_16x16x32_bf16(P1h.s, B2h[t].s, C1, 0, 0, 0);
        C1 = __builtin_amdgcn_mfma_f32_16x16x32_bf16(P1h.s, B2l[t].s, C1, 0, 0, 0);
        C1 = __builtin_amdgcn_mfma_f32_16x16x32_bf16(P1l.s, B2h[t].s, C1, 0, 0, 0);

        float u = 0.f;
        #pragma unroll
        for (int i = 0; i < 4; ++i) {
            float ha = fast_tanh(C0[i] + ob2a[i]);
            float hb = fast_tanh(C1[i] + ob2b[i]);
            u = fmaf(ha, w3o0[i], u);
            u = fmaf(hb, w3o1[i], u);
        }
        u += __shfl_xor(u, 16);
        u += __shfl_xor(u, 32);
        u += bo;
        if (g == 0 && samp[t] < N) out[samp[t]] = u;
    }
}

extern "C" void kernel_launch(void* const* d_in, const int* in_sizes, int n_in,
                              void* d_out, int out_size, void* d_ws, size_t ws_size,
                              hipStream_t stream) {
    const float* x   = (const float*)d_in[0];
    const float* pw1 = (const float*)d_in[1];
    const float* pb1 = (const float*)d_in[2];
    const float* pw2 = (const float*)d_in[3];
    const float* pb2 = (const float*)d_in[4];
    const float* pw3 = (const float*)d_in[5];
    const float* pb3 = (const float*)d_in[6];
    const float* qw  = (const float*)d_in[7];
    const float* ow1 = (const float*)d_in[8];
    const float* ob1 = (const float*)d_in[9];
    const float* ow2 = (const float*)d_in[10];
    const float* ob2 = (const float*)d_in[11];
    const float* ow3 = (const float*)d_in[12];
    const float* ob3 = (const float*)d_in[13];
    float* out = (float*)d_out;
    float* ws  = (float*)d_ws;

    const int N = in_sizes[0];

    qcpinn_setup<<<1, 64, 0, stream>>>(qw, pw2, ow2, ws);

    const int grid = (N + 63) / 64;   // 64 samples per block (2 waves x 2 tiles)
    qcpinn_main<<<grid, 128, 0, stream>>>(
        x, pw1, pb1, pb2, pw3, pb3, ws,
        ow1, ob1, ob2, ow3, ob3, out, N);
}

// Round 3
// 126.289 us; speedup vs baseline: 1.3764x; 1.0316x over previous
//
#include <hip/hip_runtime.h>
#include <math.h>
#include <stdint.h>

// ---------------------------------------------------------------------------
// QCPINN via MFMA: pre-MLP(1->32->32->2) -> fixed 4x4 complex circuit U ->
// post-MLP(2->32->32->1), N=1e6.
//
// Wave layout: 64 lanes = 4 groups (g=lane>>4) x 16 samples (s=lane&15).
// Each wave handles FOUR tiles of 16 samples (64 samples/wave), so all
// weights / A-fragments / U-rows are loaded once per wave and stay in VGPRs
// (__launch_bounds__(256,4) -> 128-VGPR budget; round-2's (128) budget of 48
// forced per-tile weight reloads).
//
// 32x32 layers: C = W^T x H^T via v_mfma_f32_16x16x32_bf16, hi/lo bf16 split
// (3 passes) for ~fp32 accuracy.
//   B-frag (H^T): lane holds h[sample=lane&15][k=(lane>>4)*8+j], j=0..7
//   A-frag (W^T): lane holds W[k=(lane>>4)*8+j][out=r*16+(lane&15)] (packed
//                 by setup kernel into d_ws)
//   C-frag:       lane holds C[out=(lane>>4)*4+i (+16 r=1)][sample=lane&15]
// Quantum middle is group-split: each group computes only its own row m=g of
// U, then two signed butterflies rebuild z0/z1 in all lanes. No LDS anywhere.
// ---------------------------------------------------------------------------

typedef __attribute__((ext_vector_type(8))) short short8;   // 8 x bf16
typedef __attribute__((ext_vector_type(4))) float f32x4;

union Frag { uint32_t u[4]; short8 s; };

// tanh(x) = 1 - 2/(exp(2x)+1); exp(2x) = 2^(x * 2*log2(e)). Saturates at +-1.
__device__ __forceinline__ float fast_tanh(float x) {
    float e = __builtin_amdgcn_exp2f(x * 2.8853900817779268f);
    return fmaf(-2.0f, __builtin_amdgcn_rcpf(e + 1.0f), 1.0f);
}

// split 8 f32 -> packed bf16 hi (4 uints) + lo (4 uints); truncation split.
__device__ __forceinline__ void split8(const float h[8], uint32_t hi[4], uint32_t lo[4]) {
    #pragma unroll
    for (int p = 0; p < 4; ++p) {
        uint32_t u0 = __float_as_uint(h[2*p])   & 0xFFFF0000u;
        uint32_t u1 = __float_as_uint(h[2*p+1]) & 0xFFFF0000u;
        float l0 = h[2*p]   - __uint_as_float(u0);
        float l1 = h[2*p+1] - __uint_as_float(u1);
        uint32_t v0 = __float_as_uint(l0) & 0xFFFF0000u;
        uint32_t v1 = __float_as_uint(l1) & 0xFFFF0000u;
        hi[p] = (u0 >> 16) | u1;   // elem 2p low short, 2p+1 high short
        lo[p] = (v0 >> 16) | v1;
    }
}

struct cplx { float re, im; };
__device__ __forceinline__ cplx cmul(cplx a, cplx b) {
    return { a.re * b.re - a.im * b.im, a.re * b.im + a.im * b.re };
}
__device__ __forceinline__ cplx cadd(cplx a, cplx b) {
    return { a.re + b.re, a.im + b.im };
}

// ---------------------------------------------------------------------------
// Setup: (a) all 64 lanes pack W2/OW2 into A-frag hi/lo order in ws;
//        (b) lane 0 computes the fixed 4x4 circuit matrix U.
// ws layout (uint32 units): [0..31] U floats (re16 row-major, im16);
//   [32 + (kind*64 + lane)*4 ..], kind = mat*4 + r*2 + (0 hi | 1 lo).
// ---------------------------------------------------------------------------
__global__ void qcpinn_setup(const float* __restrict__ qw,
                             const float* __restrict__ pw2,
                             const float* __restrict__ ow2,
                             float* __restrict__ ws) {
    const int lane = threadIdx.x & 63;
    const int s = lane & 15, gg = lane >> 4;
    uint32_t* wsu = (uint32_t*)ws;

    #pragma unroll
    for (int m = 0; m < 2; ++m) {
        const float* W = m ? ow2 : pw2;   // [32 in][32 out] row-major
        #pragma unroll
        for (int r = 0; r < 2; ++r) {
            float v[8];
            #pragma unroll
            for (int j = 0; j < 8; ++j)
                v[j] = W[(gg * 8 + j) * 32 + (r * 16 + s)];
            uint32_t hi[4], lo[4];
            split8(v, hi, lo);
            int bh = 32 + ((m * 4 + r * 2 + 0) * 64 + lane) * 4;
            int bl = 32 + ((m * 4 + r * 2 + 1) * 64 + lane) * 4;
            #pragma unroll
            for (int p = 0; p < 4; ++p) { wsu[bh + p] = hi[p]; wsu[bl + p] = lo[p]; }
        }
    }

    if (threadIdx.x == 0) {
        cplx U[16];
        for (int i = 0; i < 16; ++i) U[i] = {0.f, 0.f};
        U[0].re = U[5].re = U[10].re = U[15].re = 1.f;

        for (int l = 0; l < 2; ++l) {
            cplx g[2][4];
            for (int w = 0; w < 2; ++w) {
                float a = qw[l * 6 + w * 3 + 0];
                float b = qw[l * 6 + w * 3 + 1];
                float c = qw[l * 6 + w * 3 + 2];
                float sa, ca, sb, cb, sc, cc;
                __sincosf(0.5f * a, &sa, &ca);
                __sincosf(0.5f * b, &sb, &cb);
                __sincosf(0.5f * c, &sc, &cc);
                cplx RX[4] = {{ca, 0.f}, {0.f, -sa}, {0.f, -sa}, {ca, 0.f}};
                cplx RY[4] = {{cb, 0.f}, {-sb, 0.f}, {sb, 0.f}, {cb, 0.f}};
                cplx RZ[4] = {{cc, -sc}, {0.f, 0.f}, {0.f, 0.f}, {cc, sc}};
                cplx T[4];
                for (int i2 = 0; i2 < 2; ++i2)
                    for (int j2 = 0; j2 < 2; ++j2) {
                        cplx acc = {0.f, 0.f};
                        for (int k2 = 0; k2 < 2; ++k2)
                            acc = cadd(acc, cmul(RY[i2 * 2 + k2], RX[k2 * 2 + j2]));
                        T[i2 * 2 + j2] = acc;
                    }
                for (int i2 = 0; i2 < 2; ++i2)
                    for (int j2 = 0; j2 < 2; ++j2) {
                        cplx acc = {0.f, 0.f};
                        for (int k2 = 0; k2 < 2; ++k2)
                            acc = cadd(acc, cmul(RZ[i2 * 2 + k2], T[k2 * 2 + j2]));
                        g[w][i2 * 2 + j2] = acc;
                    }
            }
            cplx L[16];
            for (int i4 = 0; i4 < 4; ++i4) {
                int si = (i4 == 2) ? 3 : (i4 == 3) ? 2 : i4;
                for (int j4 = 0; j4 < 4; ++j4)
                    L[i4 * 4 + j4] = cmul(g[1][(si & 1) * 2 + (j4 & 1)],
                                          g[0][(si >> 1) * 2 + (j4 >> 1)]);
            }
            cplx Un[16];
            for (int i4 = 0; i4 < 4; ++i4)
                for (int j4 = 0; j4 < 4; ++j4) {
                    cplx acc = {0.f, 0.f};
                    for (int k4 = 0; k4 < 4; ++k4)
                        acc = cadd(acc, cmul(L[i4 * 4 + k4], U[k4 * 4 + j4]));
                    Un[i4 * 4 + j4] = acc;
                }
            for (int i = 0; i < 16; ++i) U[i] = Un[i];
        }
        for (int i = 0; i < 16; ++i) { ws[i] = U[i].re; ws[16 + i] = U[i].im; }
    }
}

// ---------------------------------------------------------------------------
// Main: block = 256 threads = 4 waves; wave = 4 tiles x 16 samples.
// ---------------------------------------------------------------------------
#define NT 4
__global__ __launch_bounds__(256, 4) void qcpinn_main(
    const float* __restrict__ x,
    const float* __restrict__ pw1, const float* __restrict__ pb1,
    const float* __restrict__ pb2, const float* __restrict__ pw3,
    const float* __restrict__ pb3,
    const float* __restrict__ ws,
    const float* __restrict__ ow1, const float* __restrict__ ob1,
    const float* __restrict__ ob2, const float* __restrict__ ow3,
    const float* __restrict__ ob3,
    float* __restrict__ out, int N)
{
    const int lane = threadIdx.x & 63;
    const int wid  = threadIdx.x >> 6;
    const int s    = lane & 15;
    const int g    = lane >> 4;
    const int base = (blockIdx.x * 4 + wid) * (NT * 16);

    const Frag* fragp = (const Frag*)(ws + 32);

    // ---------------- inputs ------------------------------------------------
    float xv[NT];
    #pragma unroll
    for (int t = 0; t < NT; ++t) {
        int idx = base + t * 16 + s;
        xv[t] = (idx < N) ? x[idx] : 0.f;
    }

    // ---------------- phase-1 weights (resident all phase) ------------------
    f32x4 w1a = *(const f32x4*)(pw1 + g * 8);
    f32x4 w1b = *(const f32x4*)(pw1 + g * 8 + 4);
    f32x4 b1a = *(const f32x4*)(pb1 + g * 8);
    f32x4 b1b = *(const f32x4*)(pb1 + g * 8 + 4);
    Frag A0h = fragp[0 * 64 + lane];
    Frag A0l = fragp[1 * 64 + lane];
    Frag A1h = fragp[2 * 64 + lane];
    Frag A1l = fragp[3 * 64 + lane];
    f32x4 pb2a = *(const f32x4*)(pb2 + g * 4);
    f32x4 pb2b = *(const f32x4*)(pb2 + 16 + g * 4);
    f32x4 w3a = *(const f32x4*)(pw3 + g * 8);            // rows g*4, g*4+1
    f32x4 w3b = *(const f32x4*)(pw3 + g * 8 + 4);        // rows g*4+2, +3
    f32x4 w3c = *(const f32x4*)(pw3 + 32 + g * 8);       // rows 16+g*4, +1
    f32x4 w3d = *(const f32x4*)(pw3 + 32 + g * 8 + 4);   // rows 16+g*4+2, +3
    const float bq0 = pb3[0], bq1 = pb3[1];
    // U row m=g (per-lane): re, im
    f32x4 Ure = *(const f32x4*)(ws + g * 4);
    f32x4 Uim = *(const f32x4*)(ws + 16 + g * 4);
    // z0 = sum_m sgn0(m)*p_m with sgn0 = +,+,-,- ; z1: +,-,+,-
    const float sgn0 = (g & 2) ? -1.f : 1.f;
    const float sgn1 = (g & 1) ? -1.f : 1.f;

    // ---------------- phase 1: pre-MLP + quantum per tile -------------------
    float z0[NT], z1[NT];
    #pragma unroll
    for (int t = 0; t < NT; ++t) {
        // pre layer 1: 1 -> 32 (B-frag directly)
        float h[8];
        #pragma unroll
        for (int j = 0; j < 4; ++j) {
            h[j]     = fast_tanh(fmaf(xv[t], w1a[j], b1a[j]));
            h[4 + j] = fast_tanh(fmaf(xv[t], w1b[j], b1b[j]));
        }
        Frag Bh, Bl;
        split8(h, Bh.u, Bl.u);

        // pre layer 2: 32 -> 32 via MFMA (hi/lo 3-pass)
        f32x4 C0 = {0.f, 0.f, 0.f, 0.f};
        f32x4 C1 = {0.f, 0.f, 0.f, 0.f};
        C0 = __builtin_amdgcn_mfma_f32_16x16x32_bf16(A0h.s, Bh.s, C0, 0, 0, 0);
        C0 = __builtin_amdgcn_mfma_f32_16x16x32_bf16(A0h.s, Bl.s, C0, 0, 0, 0);
        C0 = __builtin_amdgcn_mfma_f32_16x16x32_bf16(A0l.s, Bh.s, C0, 0, 0, 0);
        C1 = __builtin_amdgcn_mfma_f32_16x16x32_bf16(A1h.s, Bh.s, C1, 0, 0, 0);
        C1 = __builtin_amdgcn_mfma_f32_16x16x32_bf16(A1h.s, Bl.s, C1, 0, 0, 0);
        C1 = __builtin_amdgcn_mfma_f32_16x16x32_bf16(A1l.s, Bh.s, C1, 0, 0, 0);

        float h2[8];
        #pragma unroll
        for (int i = 0; i < 4; ++i) {
            h2[i]     = fast_tanh(C0[i] + pb2a[i]);
            h2[4 + i] = fast_tanh(C1[i] + pb2b[i]);
        }

        // pre layer 3: 32 -> 2 (partial dots + butterfly over groups)
        float q0 = 0.f, q1 = 0.f;
        q0 = fmaf(h2[0], w3a[0], q0); q1 = fmaf(h2[0], w3a[1], q1);
        q0 = fmaf(h2[1], w3a[2], q0); q1 = fmaf(h2[1], w3a[3], q1);
        q0 = fmaf(h2[2], w3b[0], q0); q1 = fmaf(h2[2], w3b[1], q1);
        q0 = fmaf(h2[3], w3b[2], q0); q1 = fmaf(h2[3], w3b[3], q1);
        q0 = fmaf(h2[4], w3c[0], q0); q1 = fmaf(h2[4], w3c[1], q1);
        q0 = fmaf(h2[5], w3c[2], q0); q1 = fmaf(h2[5], w3c[3], q1);
        q0 = fmaf(h2[6], w3d[0], q0); q1 = fmaf(h2[6], w3d[1], q1);
        q0 = fmaf(h2[7], w3d[2], q0); q1 = fmaf(h2[7], w3d[3], q1);
        q0 += __shfl_xor(q0, 16); q0 += __shfl_xor(q0, 32); q0 += bq0;
        q1 += __shfl_xor(q1, 16); q1 += __shfl_xor(q1, 32); q1 += bq1;

        // quantum: e = rank-1 real encoding, v_m = (U e)_m for m = g only
        float s0, c0, s1, c1;
        __sincosf(0.5f * q0, &s0, &c0);
        __sincosf(0.5f * q1, &s1, &c1);
        float e0 = c0 * c1, e1 = c0 * s1, e2 = s0 * c1, e3 = s0 * s1;
        float re = fmaf(Ure[0], e0, fmaf(Ure[1], e1, fmaf(Ure[2], e2, Ure[3] * e3)));
        float im = fmaf(Uim[0], e0, fmaf(Uim[1], e1, fmaf(Uim[2], e2, Uim[3] * e3)));
        float p  = fmaf(re, re, im * im);
        float t0 = sgn0 * p, t1 = sgn1 * p;
        t0 += __shfl_xor(t0, 16); t0 += __shfl_xor(t0, 32);
        t1 += __shfl_xor(t1, 16); t1 += __shfl_xor(t1, 32);
        z0[t] = t0; z1[t] = t1;
    }

    // ---------------- phase-2 weights ---------------------------------------
    f32x4 oa   = *(const f32x4*)(ow1 + g * 8);
    f32x4 oa2  = *(const f32x4*)(ow1 + g * 8 + 4);
    f32x4 obv  = *(const f32x4*)(ow1 + 32 + g * 8);
    f32x4 ob2v = *(const f32x4*)(ow1 + 32 + g * 8 + 4);
    f32x4 obb  = *(const f32x4*)(ob1 + g * 8);
    f32x4 obb2 = *(const f32x4*)(ob1 + g * 8 + 4);
    Frag P0h = fragp[4 * 64 + lane];
    Frag P0l = fragp[5 * 64 + lane];
    Frag P1h = fragp[6 * 64 + lane];
    Frag P1l = fragp[7 * 64 + lane];
    f32x4 ob2a = *(const f32x4*)(ob2 + g * 4);
    f32x4 ob2b = *(const f32x4*)(ob2 + 16 + g * 4);
    f32x4 w3o0 = *(const f32x4*)(ow3 + g * 4);
    f32x4 w3o1 = *(const f32x4*)(ow3 + 16 + g * 4);
    const float bo = ob3[0];

    // ---------------- phase 2: post-MLP per tile ----------------------------
    #pragma unroll
    for (int t = 0; t < NT; ++t) {
        float h[8];
        #pragma unroll
        for (int j = 0; j < 4; ++j) {
            h[j]     = fast_tanh(fmaf(z0[t], oa[j],  fmaf(z1[t], obv[j],  obb[j])));
            h[4 + j] = fast_tanh(fmaf(z0[t], oa2[j], fmaf(z1[t], ob2v[j], obb2[j])));
        }
        Frag Bh, Bl;
        split8(h, Bh.u, Bl.u);

        f32x4 C0 = {0.f, 0.f, 0.f, 0.f};
        f32x4 C1 = {0.f, 0.f, 0.f, 0.f};
        C0 = __builtin_amdgcn_mfma_f32_16x16x32_bf16(P0h.s, Bh.s, C0, 0, 0, 0);
        C0 = __builtin_amdgcn_mfma_f32_16x16x32_bf16(P0h.s, Bl.s, C0, 0, 0, 0);
        C0 = __builtin_amdgcn_mfma_f32_16x16x32_bf16(P0l.s, Bh.s, C0, 0, 0, 0);
        C1 = __builtin_amdgcn_mfma_f32_16x16x32_bf16(P1h.s, Bh.s, C1, 0, 0, 0);
        C1 = __builtin_amdgcn_mfma_f32_16x16x32_bf16(P1h.s, Bl.s, C1, 0, 0, 0);
        C1 = __builtin_amdgcn_mfma_f32_16x16x32_bf16(P1l.s, Bh.s, C1, 0, 0, 0);

        float u = 0.f;
        #pragma unroll
        for (int i = 0; i < 4; ++i) {
            float ha = fast_tanh(C0[i] + ob2a[i]);
            float hb = fast_tanh(C1[i] + ob2b[i]);
            u = fmaf(ha, w3o0[i], u);
            u = fmaf(hb, w3o1[i], u);
        }
        u += __shfl_xor(u, 16);
        u += __shfl_xor(u, 32);
        u += bo;
        int idx = base + t * 16 + s;
        if (g == 0 && idx < N) out[idx] = u;
    }
}

extern "C" void kernel_launch(void* const* d_in, const int* in_sizes, int n_in,
                              void* d_out, int out_size, void* d_ws, size_t ws_size,
                              hipStream_t stream) {
    const float* x   = (const float*)d_in[0];
    const float* pw1 = (const float*)d_in[1];
    const float* pb1 = (const float*)d_in[2];
    const float* pw2 = (const float*)d_in[3];
    const float* pb2 = (const float*)d_in[4];
    const float* pw3 = (const float*)d_in[5];
    const float* pb3 = (const float*)d_in[6];
    const float* qw  = (const float*)d_in[7];
    const float* ow1 = (const float*)d_in[8];
    const float* ob1 = (const float*)d_in[9];
    const float* ow2 = (const float*)d_in[10];
    const float* ob2 = (const float*)d_in[11];
    const float* ow3 = (const float*)d_in[12];
    const float* ob3 = (const float*)d_in[13];
    float* out = (float*)d_out;
    float* ws  = (float*)d_ws;

    const int N = in_sizes[0];

    qcpinn_setup<<<1, 64, 0, stream>>>(qw, pw2, ow2, ws);

    const int grid = (N + 255) / 256;   // 256 samples per block (4 waves x 4 tiles)
    qcpinn_main<<<grid, 256, 0, stream>>>(
        x, pw1, pb1, pb2, pw3, pb3, ws,
        ow1, ob1, ob2, ow3, ob3, out, N);
}

// Round 4
// 118.799 us; speedup vs baseline: 1.4631x; 1.0630x over previous
//
#include <hip/hip_runtime.h>
#include <hip/hip_bf16.h>
#include <math.h>
#include <stdint.h>

// ---------------------------------------------------------------------------
// QCPINN: pre-MLP(1->32->32->2,tanh) -> fixed 4x4 complex circuit U ->
// post-MLP(2->32->32->1,tanh), N=1e6.  Entirely VALU/trans-bound.
//
// Key transforms (all baked by the setup kernel into a 9.7KB LDS image):
//  * tanh(x) = 1 - 2*sig(K*x), sig(y) = rcp(exp2(y)+1), K = 2*log2(e).
//    The affine (1 - 2*r) is folded into the NEXT layer's weights/biases:
//    W' = -2K*W, b' = K*(b + colsum(W)).  tanh body: exp2, add, rcp (3 ops).
//  * Biases are MFMA-accumulator init values (no adds).
//  * 0.5 factor for sincos folded into pw3/pb3.
//  * Butterfly sign patterns for z0/z1 baked into ow1's sign per feature block.
//  * 32x32 layers on MFMA, 2-pass weight-split (Ahi+Alo) x RNE-bf16 acts.
//
// Wave layout: 64 lanes = 4 groups (g) x 16 samples (s); 4 tiles/wave = 64
// samples/wave; block = 4 waves = 256 samples.
// ---------------------------------------------------------------------------

typedef __attribute__((ext_vector_type(8))) short short8;
typedef __attribute__((ext_vector_type(4))) float f32x4;

union Frag { uint32_t u[4]; short8 s; };

#define KT 2.8853900817779268f   // 2*log2(e)

// LDS image layout (float indices)
#define L_FRAG 0      // 8 frags x 64 lanes x 4 words = 2048
#define L_U    2048   // 32: circuit matrix (re16 row-major, im16)
#define L_W1   2080   // 32: KT*pw1
#define L_B1   2112   // 32: KT*pb1
#define L_BH2  2144   // 32: KT*(pb2 + colsum pw2)
#define L_W3   2176   // 64: -pw3  ([32][2] row-major)
#define L_OW1  2240   // 64: KT*sgn-baked ow1 ([2][32] row-major)
#define L_OB1  2304   // 32: KT*ob1
#define L_BH2P 2336   // 32: KT*(ob2 + colsum ow2)
#define L_OW3  2368   // 32: -2*ow3
#define L_SC   2400   // [0]=.5*(pb3[0]+colsum pw3_0) [1]=same col1 [2]=ob3+colsum ow3
#define L_TOT  2416   // = 604 float4

__device__ __forceinline__ float sig_act(float y) {
    return __builtin_amdgcn_rcpf(__builtin_amdgcn_exp2f(y) + 1.0f);
}

__device__ __forceinline__ uint32_t pk_bf16(float a, float b) {
    union { __hip_bfloat162 h; uint32_t u; } cv;
    cv.h.x = __float2bfloat16(a);
    cv.h.y = __float2bfloat16(b);
    return cv.u;   // a in low short, b in high short
}

// truncation hi/lo split for (pre-scaled) weights; combined ~2^-17 rel.
__device__ __forceinline__ void split8(const float h[8], uint32_t hi[4], uint32_t lo[4]) {
    #pragma unroll
    for (int p = 0; p < 4; ++p) {
        uint32_t u0 = __float_as_uint(h[2*p])   & 0xFFFF0000u;
        uint32_t u1 = __float_as_uint(h[2*p+1]) & 0xFFFF0000u;
        float l0 = h[2*p]   - __uint_as_float(u0);
        float l1 = h[2*p+1] - __uint_as_float(u1);
        uint32_t v0 = __float_as_uint(l0) & 0xFFFF0000u;
        uint32_t v1 = __float_as_uint(l1) & 0xFFFF0000u;
        hi[p] = (u0 >> 16) | u1;
        lo[p] = (v0 >> 16) | v1;
    }
}

struct cplx { float re, im; };
__device__ __forceinline__ cplx cmul(cplx a, cplx b) {
    return { a.re * b.re - a.im * b.im, a.re * b.im + a.im * b.re };
}
__device__ __forceinline__ cplx cadd(cplx a, cplx b) {
    return { a.re + b.re, a.im + b.im };
}

// ---------------------------------------------------------------------------
// Setup (1 wave): builds the complete transformed LDS image in ws.
// ---------------------------------------------------------------------------
__global__ void qcpinn_setup(
    const float* __restrict__ pw1, const float* __restrict__ pb1,
    const float* __restrict__ pw2, const float* __restrict__ pb2,
    const float* __restrict__ pw3, const float* __restrict__ pb3,
    const float* __restrict__ qw,
    const float* __restrict__ ow1, const float* __restrict__ ob1,
    const float* __restrict__ ow2, const float* __restrict__ ob2,
    const float* __restrict__ ow3, const float* __restrict__ ob3,
    float* __restrict__ ws)
{
    const int lane = threadIdx.x & 63;
    const int s = lane & 15, gg = lane >> 4;
    uint32_t* wsu = (uint32_t*)ws;

    // fragments: Ahat = -2*KT*W, split hi/lo. frag k = m*4 + r*2 + (0 hi|1 lo)
    #pragma unroll
    for (int m = 0; m < 2; ++m) {
        const float* W = m ? ow2 : pw2;   // [32 in][32 out] row-major
        #pragma unroll
        for (int r = 0; r < 2; ++r) {
            float v[8];
            #pragma unroll
            for (int j = 0; j < 8; ++j)
                v[j] = -2.0f * KT * W[(gg * 8 + j) * 32 + (r * 16 + s)];
            uint32_t hi[4], lo[4];
            split8(v, hi, lo);
            int bh = L_FRAG + ((m * 4 + r * 2 + 0) * 256) + lane * 4;
            int bl = L_FRAG + ((m * 4 + r * 2 + 1) * 256) + lane * 4;
            #pragma unroll
            for (int p = 0; p < 4; ++p) { wsu[bh + p] = hi[p]; wsu[bl + p] = lo[p]; }
        }
    }

    if (lane < 32) {
        int j = lane;
        float cs_p = 0.f, cs_o = 0.f;
        for (int k = 0; k < 32; ++k) { cs_p += pw2[k * 32 + j]; cs_o += ow2[k * 32 + j]; }
        ws[L_W1 + j]   = KT * pw1[j];
        ws[L_B1 + j]   = KT * pb1[j];
        ws[L_BH2 + j]  = KT * (pb2[j] + cs_p);
        ws[L_OB1 + j]  = KT * ob1[j];
        ws[L_BH2P + j] = KT * (ob2[j] + cs_o);
        ws[L_OW3 + j]  = -2.f * ow3[j];
        ws[L_W3 + j * 2]     = -pw3[j * 2];
        ws[L_W3 + j * 2 + 1] = -pw3[j * 2 + 1];
        // z-butterfly leaves sgn0(g)=+,+,-,- (g&2) on z0, sgn1(g)=+,-,+,- (g&1)
        // on z1; feature j belongs to group j>>3 -> bake signs here.
        float sg0 = (j & 16) ? -1.f : 1.f;
        float sg1 = (j & 8)  ? -1.f : 1.f;
        ws[L_OW1 + j]      = KT * sg0 * ow1[j];
        ws[L_OW1 + 32 + j] = KT * sg1 * ow1[32 + j];
    }

    if (lane == 0) {
        float cw0 = 0.f, cw1 = 0.f, co3 = 0.f;
        for (int k = 0; k < 32; ++k) {
            cw0 += pw3[k * 2]; cw1 += pw3[k * 2 + 1]; co3 += ow3[k];
        }
        ws[L_SC + 0] = 0.5f * (pb3[0] + cw0);
        ws[L_SC + 1] = 0.5f * (pb3[1] + cw1);
        ws[L_SC + 2] = ob3[0] + co3;
        ws[L_SC + 3] = 0.f;

        // fixed circuit matrix U = L1*L0, Ll = P*(g0 (x) g1), g = RZ*RY*RX
        cplx U[16];
        for (int i = 0; i < 16; ++i) U[i] = {0.f, 0.f};
        U[0].re = U[5].re = U[10].re = U[15].re = 1.f;
        for (int l = 0; l < 2; ++l) {
            cplx g[2][4];
            for (int w = 0; w < 2; ++w) {
                float a = qw[l * 6 + w * 3 + 0];
                float b = qw[l * 6 + w * 3 + 1];
                float c = qw[l * 6 + w * 3 + 2];
                float sa, ca, sb, cb, sc, cc;
                __sincosf(0.5f * a, &sa, &ca);
                __sincosf(0.5f * b, &sb, &cb);
                __sincosf(0.5f * c, &sc, &cc);
                cplx RX[4] = {{ca, 0.f}, {0.f, -sa}, {0.f, -sa}, {ca, 0.f}};
                cplx RY[4] = {{cb, 0.f}, {-sb, 0.f}, {sb, 0.f}, {cb, 0.f}};
                cplx RZ[4] = {{cc, -sc}, {0.f, 0.f}, {0.f, 0.f}, {cc, sc}};
                cplx T[4];
                for (int i2 = 0; i2 < 2; ++i2)
                    for (int j2 = 0; j2 < 2; ++j2) {
                        cplx acc = {0.f, 0.f};
                        for (int k2 = 0; k2 < 2; ++k2)
                            acc = cadd(acc, cmul(RY[i2 * 2 + k2], RX[k2 * 2 + j2]));
                        T[i2 * 2 + j2] = acc;
                    }
                for (int i2 = 0; i2 < 2; ++i2)
                    for (int j2 = 0; j2 < 2; ++j2) {
                        cplx acc = {0.f, 0.f};
                        for (int k2 = 0; k2 < 2; ++k2)
                            acc = cadd(acc, cmul(RZ[i2 * 2 + k2], T[k2 * 2 + j2]));
                        g[w][i2 * 2 + j2] = acc;
                    }
            }
            cplx L[16];
            for (int i4 = 0; i4 < 4; ++i4) {
                int si = (i4 == 2) ? 3 : (i4 == 3) ? 2 : i4;
                for (int j4 = 0; j4 < 4; ++j4)
                    L[i4 * 4 + j4] = cmul(g[1][(si & 1) * 2 + (j4 & 1)],
                                          g[0][(si >> 1) * 2 + (j4 >> 1)]);
            }
            cplx Un[16];
            for (int i4 = 0; i4 < 4; ++i4)
                for (int j4 = 0; j4 < 4; ++j4) {
                    cplx acc = {0.f, 0.f};
                    for (int k4 = 0; k4 < 4; ++k4)
                        acc = cadd(acc, cmul(L[i4 * 4 + k4], U[k4 * 4 + j4]));
                    Un[i4 * 4 + j4] = acc;
                }
            for (int i = 0; i < 16; ++i) U[i] = Un[i];
        }
        for (int i = 0; i < 16; ++i) { ws[L_U + i] = U[i].re; ws[L_U + 16 + i] = U[i].im; }
    }
}

// ---------------------------------------------------------------------------
// Main: block = 256 = 4 waves; wave = 4 tiles x 16 samples = 64 samples.
// ---------------------------------------------------------------------------
#define NT 4
__global__ __launch_bounds__(256) void qcpinn_main(
    const float* __restrict__ x, const float* __restrict__ ws,
    float* __restrict__ out, int N)
{
    __shared__ float lds[L_TOT];
    {
        const float4* src = (const float4*)ws;
        float4* dst = (float4*)lds;
        for (int i = threadIdx.x; i < L_TOT / 4; i += 256) dst[i] = src[i];
    }
    __syncthreads();

    const int lane = threadIdx.x & 63;
    const int wid  = threadIdx.x >> 6;
    const int s    = lane & 15;
    const int g    = lane >> 4;
    const int base = (blockIdx.x * 4 + wid) * 64;

    const Frag* frag = (const Frag*)(lds + L_FRAG);

    float xv[NT];
    #pragma unroll
    for (int t = 0; t < NT; ++t) {
        int idx = base + t * 16 + s;
        xv[t] = (idx < N) ? x[idx] : 0.f;
    }

    // per-group weight vectors (LDS-resident; compiler hoists what fits)
    f32x4 w1a = *(const f32x4*)(lds + L_W1 + g * 8);
    f32x4 w1b = *(const f32x4*)(lds + L_W1 + g * 8 + 4);
    f32x4 b1a = *(const f32x4*)(lds + L_B1 + g * 8);
    f32x4 b1b = *(const f32x4*)(lds + L_B1 + g * 8 + 4);
    Frag A0h = frag[0 * 64 + lane], A0l = frag[1 * 64 + lane];
    Frag A1h = frag[2 * 64 + lane], A1l = frag[3 * 64 + lane];
    f32x4 bh2a = *(const f32x4*)(lds + L_BH2 + g * 4);
    f32x4 bh2b = *(const f32x4*)(lds + L_BH2 + 16 + g * 4);
    f32x4 w3a = *(const f32x4*)(lds + L_W3 + g * 8);
    f32x4 w3b = *(const f32x4*)(lds + L_W3 + g * 8 + 4);
    f32x4 w3c = *(const f32x4*)(lds + L_W3 + 32 + g * 8);
    f32x4 w3d = *(const f32x4*)(lds + L_W3 + 32 + g * 8 + 4);
    f32x4 Ure = *(const f32x4*)(lds + L_U + g * 4);
    f32x4 Uim = *(const f32x4*)(lds + L_U + 16 + g * 4);
    const float qb0 = lds[L_SC + 0], qb1 = lds[L_SC + 1], bo = lds[L_SC + 2];
    f32x4 oa   = *(const f32x4*)(lds + L_OW1 + g * 8);
    f32x4 oa2  = *(const f32x4*)(lds + L_OW1 + g * 8 + 4);
    f32x4 obv  = *(const f32x4*)(lds + L_OW1 + 32 + g * 8);
    f32x4 ob2v = *(const f32x4*)(lds + L_OW1 + 32 + g * 8 + 4);
    f32x4 obb  = *(const f32x4*)(lds + L_OB1 + g * 8);
    f32x4 obb2 = *(const f32x4*)(lds + L_OB1 + g * 8 + 4);
    Frag P0h = frag[4 * 64 + lane], P0l = frag[5 * 64 + lane];
    Frag P1h = frag[6 * 64 + lane], P1l = frag[7 * 64 + lane];
    f32x4 bpa = *(const f32x4*)(lds + L_BH2P + g * 4);
    f32x4 bpb = *(const f32x4*)(lds + L_BH2P + 16 + g * 4);
    f32x4 w3o0 = *(const f32x4*)(lds + L_OW3 + g * 4);
    f32x4 w3o1 = *(const f32x4*)(lds + L_OW3 + 16 + g * 4);

    float uo[NT];
    #pragma unroll
    for (int t = 0; t < NT; ++t) {
        // pre layer 1: r1 = sig(KT*(w1*x+b1))  (scales pre-baked)
        float r1[8];
        #pragma unroll
        for (int j = 0; j < 4; ++j) {
            r1[j]     = sig_act(fmaf(xv[t], w1a[j], b1a[j]));
            r1[4 + j] = sig_act(fmaf(xv[t], w1b[j], b1b[j]));
        }
        Frag B;
        #pragma unroll
        for (int p = 0; p < 4; ++p) B.u[p] = pk_bf16(r1[2*p], r1[2*p+1]);

        // pre layer 2 (MFMA, 2-pass weight split, bias-init accumulators)
        f32x4 C0 = bh2a, C1 = bh2b;
        C0 = __builtin_amdgcn_mfma_f32_16x16x32_bf16(A0h.s, B.s, C0, 0, 0, 0);
        C0 = __builtin_amdgcn_mfma_f32_16x16x32_bf16(A0l.s, B.s, C0, 0, 0, 0);
        C1 = __builtin_amdgcn_mfma_f32_16x16x32_bf16(A1h.s, B.s, C1, 0, 0, 0);
        C1 = __builtin_amdgcn_mfma_f32_16x16x32_bf16(A1l.s, B.s, C1, 0, 0, 0);
        float r2[8];
        #pragma unroll
        for (int i = 0; i < 4; ++i) { r2[i] = sig_act(C0[i]); r2[4+i] = sig_act(C1[i]); }

        // pre layer 3 partial dots (weights = -pw3; bias folded into qb)
        float q0, q1;
        q0 = r2[0] * w3a[0];           q1 = r2[0] * w3a[1];
        q0 = fmaf(r2[1], w3a[2], q0);  q1 = fmaf(r2[1], w3a[3], q1);
        q0 = fmaf(r2[2], w3b[0], q0);  q1 = fmaf(r2[2], w3b[1], q1);
        q0 = fmaf(r2[3], w3b[2], q0);  q1 = fmaf(r2[3], w3b[3], q1);
        q0 = fmaf(r2[4], w3c[0], q0);  q1 = fmaf(r2[4], w3c[1], q1);
        q0 = fmaf(r2[5], w3c[2], q0);  q1 = fmaf(r2[5], w3c[3], q1);
        q0 = fmaf(r2[6], w3d[0], q0);  q1 = fmaf(r2[6], w3d[1], q1);
        q0 = fmaf(r2[7], w3d[2], q0);  q1 = fmaf(r2[7], w3d[3], q1);
        q0 += __shfl_xor(q0, 16); q0 += __shfl_xor(q0, 32); q0 += qb0;
        q1 += __shfl_xor(q1, 16); q1 += __shfl_xor(q1, 32); q1 += qb1;

        // quantum: p = |(U e)_g|^2, group-split row
        float s0, c0, s1, c1;
        __sincosf(q0, &s0, &c0);   // q0,q1 already halved
        __sincosf(q1, &s1, &c1);
        float e0 = c0 * c1, e1 = c0 * s1, e2 = s0 * c1, e3 = s0 * s1;
        float re = fmaf(Ure[0], e0, fmaf(Ure[1], e1, fmaf(Ure[2], e2, Ure[3] * e3)));
        float im = fmaf(Uim[0], e0, fmaf(Uim[1], e1, fmaf(Uim[2], e2, Uim[3] * e3)));
        float p  = fmaf(re, re, im * im);

        // z-butterfly (signs left as sgn0(g)/sgn1(g), baked into ow1)
        float pr   = __shfl_xor(p, 16);
        float sm   = p + pr, df = p - pr;
        float z0pm = sm - __shfl_xor(sm, 32);
        float z1pm = df + __shfl_xor(df, 32);

        // post layer 1: r3 = sig(KT*(z0*w + z1*w' + b)) (signs+scale baked)
        float r3[8];
        #pragma unroll
        for (int j = 0; j < 4; ++j) {
            r3[j]     = sig_act(fmaf(z0pm, oa[j],  fmaf(z1pm, obv[j],  obb[j])));
            r3[4 + j] = sig_act(fmaf(z0pm, oa2[j], fmaf(z1pm, ob2v[j], obb2[j])));
        }
        Frag B2;
        #pragma unroll
        for (int p2 = 0; p2 < 4; ++p2) B2.u[p2] = pk_bf16(r3[2*p2], r3[2*p2+1]);

        // post layer 2 (MFMA) + layer 3 partial dot
        f32x4 D0 = bpa, D1 = bpb;
        D0 = __builtin_amdgcn_mfma_f32_16x16x32_bf16(P0h.s, B2.s, D0, 0, 0, 0);
        D0 = __builtin_amdgcn_mfma_f32_16x16x32_bf16(P0l.s, B2.s, D0, 0, 0, 0);
        D1 = __builtin_amdgcn_mfma_f32_16x16x32_bf16(P1h.s, B2.s, D1, 0, 0, 0);
        D1 = __builtin_amdgcn_mfma_f32_16x16x32_bf16(P1l.s, B2.s, D1, 0, 0, 0);

        float u = 0.f;
        #pragma unroll
        for (int i = 0; i < 4; ++i) {
            u = fmaf(sig_act(D0[i]), w3o0[i], u);
            u = fmaf(sig_act(D1[i]), w3o1[i], u);
        }
        u += __shfl_xor(u, 16);
        u += __shfl_xor(u, 32);
        uo[t] = u;
    }

    // coalesced store: lane (g,s) owns sample base + g*16 + s = base + lane
    float ua = (g & 1) ? uo[1] : uo[0];
    float ub = (g & 1) ? uo[3] : uo[2];
    float us = ((g & 2) ? ub : ua) + bo;
    int oidx = base + lane;
    if (oidx < N) out[oidx] = us;
}

extern "C" void kernel_launch(void* const* d_in, const int* in_sizes, int n_in,
                              void* d_out, int out_size, void* d_ws, size_t ws_size,
                              hipStream_t stream) {
    const float* x   = (const float*)d_in[0];
    const float* pw1 = (const float*)d_in[1];
    const float* pb1 = (const float*)d_in[2];
    const float* pw2 = (const float*)d_in[3];
    const float* pb2 = (const float*)d_in[4];
    const float* pw3 = (const float*)d_in[5];
    const float* pb3 = (const float*)d_in[6];
    const float* qw  = (const float*)d_in[7];
    const float* ow1 = (const float*)d_in[8];
    const float* ob1 = (const float*)d_in[9];
    const float* ow2 = (const float*)d_in[10];
    const float* ob2 = (const float*)d_in[11];
    const float* ow3 = (const float*)d_in[12];
    const float* ob3 = (const float*)d_in[13];
    float* out = (float*)d_out;
    float* ws  = (float*)d_ws;

    const int N = in_sizes[0];

    qcpinn_setup<<<1, 64, 0, stream>>>(pw1, pb1, pw2, pb2, pw3, pb3, qw,
                                       ow1, ob1, ow2, ob2, ow3, ob3, ws);

    const int grid = (N + 255) / 256;
    qcpinn_main<<<grid, 256, 0, stream>>>(x, ws, out, N);
}

// Round 7
// 117.538 us; speedup vs baseline: 1.4788x; 1.0107x over previous
//
#include <hip/hip_runtime.h>
#include <hip/hip_bf16.h>
#include <math.h>
#include <stdint.h>

// ---------------------------------------------------------------------------
// QCPINN: pre-MLP(1->32->32->2,tanh) -> fixed 4x4 complex circuit U ->
// post-MLP(2->32->32->1,tanh), N=1e6.  Combined VALU+trans bound.
//
// Round-5 changes (fixed: sincos via scalar temps; vector elems not addressable):
//  * float2 (v_pk_fma_f32) packed math across TILE PAIRS for every per-lane
//    fma chain (layer1, layer3 dots, quantum row, post layer1, final dot).
//  * NT=8 tiles/wave (4 independent pair-chains) so one pair's trans ops
//    overlap another pair's VALU/MFMA within the same wave.
//  * setup colsums parallelized across 64 lanes.
// Inherited: LDS weight image, tanh->sig folding (W'=-2K W, b'=K(b+colsum)),
// bias-as-accumulator-init, sign/scale baking, 2-pass weight-split MFMA.
// ---------------------------------------------------------------------------

typedef __attribute__((ext_vector_type(8))) short short8;
typedef __attribute__((ext_vector_type(4))) float f32x4;
typedef __attribute__((ext_vector_type(2))) float f32x2;

union Frag { uint32_t u[4]; short8 s; };

#define KT 2.8853900817779268f   // 2*log2(e)

// LDS image layout (float indices)
#define L_FRAG 0      // 8 frags x 64 lanes x 4 words = 2048
#define L_U    2048   // 32: circuit matrix (re16 row-major, im16)
#define L_W1   2080   // 32: KT*pw1
#define L_B1   2112   // 32: KT*pb1
#define L_BH2  2144   // 32: KT*(pb2 + colsum pw2)
#define L_W3   2176   // 64: -pw3  ([32][2] row-major)
#define L_OW1  2240   // 64: KT*sgn-baked ow1 ([2][32] row-major)
#define L_OB1  2304   // 32: KT*ob1
#define L_BH2P 2336   // 32: KT*(ob2 + colsum ow2)
#define L_OW3  2368   // 32: -2*ow3
#define L_SC   2400   // [0],[1]=.5*(pb3+colsum pw3); [2]=ob3+colsum ow3
#define L_TOT  2416

__device__ __forceinline__ f32x2 splat2(float v) { return (f32x2){v, v}; }
__device__ __forceinline__ f32x2 fma2(f32x2 a, f32x2 b, f32x2 c) {
    return __builtin_elementwise_fma(a, b, c);
}
__device__ __forceinline__ f32x2 sig2(f32x2 y) {   // rcp(exp2(y)+1) per elem
    f32x2 e;
    e.x = __builtin_amdgcn_exp2f(y.x);
    e.y = __builtin_amdgcn_exp2f(y.y);
    e = e + 1.0f;
    f32x2 r;
    r.x = __builtin_amdgcn_rcpf(e.x);
    r.y = __builtin_amdgcn_rcpf(e.y);
    return r;
}
__device__ __forceinline__ f32x2 shfl2(f32x2 v, int m) {
    f32x2 r; r.x = __shfl_xor(v.x, m); r.y = __shfl_xor(v.y, m); return r;
}
__device__ __forceinline__ uint32_t pk_bf16(float a, float b) {
    union { __hip_bfloat162 h; uint32_t u; } cv;
    cv.h.x = __float2bfloat16(a);
    cv.h.y = __float2bfloat16(b);
    return cv.u;
}

// truncation hi/lo split for pre-scaled weights
__device__ __forceinline__ void split8(const float h[8], uint32_t hi[4], uint32_t lo[4]) {
    #pragma unroll
    for (int p = 0; p < 4; ++p) {
        uint32_t u0 = __float_as_uint(h[2*p])   & 0xFFFF0000u;
        uint32_t u1 = __float_as_uint(h[2*p+1]) & 0xFFFF0000u;
        float l0 = h[2*p]   - __uint_as_float(u0);
        float l1 = h[2*p+1] - __uint_as_float(u1);
        uint32_t v0 = __float_as_uint(l0) & 0xFFFF0000u;
        uint32_t v1 = __float_as_uint(l1) & 0xFFFF0000u;
        hi[p] = (u0 >> 16) | u1;
        lo[p] = (v0 >> 16) | v1;
    }
}

struct cplx { float re, im; };
__device__ __forceinline__ cplx cmul(cplx a, cplx b) {
    return { a.re * b.re - a.im * b.im, a.re * b.im + a.im * b.re };
}
__device__ __forceinline__ cplx cadd(cplx a, cplx b) {
    return { a.re + b.re, a.im + b.im };
}

// ---------------------------------------------------------------------------
// Setup (1 wave): builds the transformed LDS image in ws.
// ---------------------------------------------------------------------------
__global__ void qcpinn_setup(
    const float* __restrict__ pw1, const float* __restrict__ pb1,
    const float* __restrict__ pw2, const float* __restrict__ pb2,
    const float* __restrict__ pw3, const float* __restrict__ pb3,
    const float* __restrict__ qw,
    const float* __restrict__ ow1, const float* __restrict__ ob1,
    const float* __restrict__ ow2, const float* __restrict__ ob2,
    const float* __restrict__ ow3, const float* __restrict__ ob3,
    float* __restrict__ ws)
{
    const int lane = threadIdx.x & 63;
    const int s = lane & 15, gg = lane >> 4;
    uint32_t* wsu = (uint32_t*)ws;

    // fragments: Ahat = -2*KT*W, split hi/lo. frag k = m*4 + r*2 + (0 hi|1 lo)
    #pragma unroll
    for (int m = 0; m < 2; ++m) {
        const float* W = m ? ow2 : pw2;   // [32 in][32 out] row-major
        #pragma unroll
        for (int r = 0; r < 2; ++r) {
            float v[8];
            #pragma unroll
            for (int j = 0; j < 8; ++j)
                v[j] = -2.0f * KT * W[(gg * 8 + j) * 32 + (r * 16 + s)];
            uint32_t hi[4], lo[4];
            split8(v, hi, lo);
            int bh = L_FRAG + ((m * 4 + r * 2 + 0) * 256) + lane * 4;
            int bl = L_FRAG + ((m * 4 + r * 2 + 1) * 256) + lane * 4;
            #pragma unroll
            for (int p = 0; p < 4; ++p) { wsu[bh + p] = hi[p]; wsu[bl + p] = lo[p]; }
        }
    }

    // colsums split across all 64 lanes (lane<32: pw2, lane>=32: ow2)
    {
        int j = lane & 31;
        const float* W = (lane < 32) ? pw2 : ow2;
        float cs = 0.f;
        for (int k = 0; k < 32; ++k) cs += W[k * 32 + j];
        if (lane < 32) ws[L_BH2  + j] = KT * (pb2[j] + cs);
        else           ws[L_BH2P + j] = KT * (ob2[j] + cs);
    }

    if (lane < 32) {
        int j = lane;
        ws[L_W1 + j]  = KT * pw1[j];
        ws[L_B1 + j]  = KT * pb1[j];
        ws[L_OB1 + j] = KT * ob1[j];
        ws[L_OW3 + j] = -2.f * ow3[j];
        ws[L_W3 + j * 2]     = -pw3[j * 2];
        ws[L_W3 + j * 2 + 1] = -pw3[j * 2 + 1];
        // z-butterfly leaves sgn0(g)=+,+,-,- (g&2) on z0, sgn1(g)=+,-,+,- (g&1)
        float sg0 = (j & 16) ? -1.f : 1.f;
        float sg1 = (j & 8)  ? -1.f : 1.f;
        ws[L_OW1 + j]      = KT * sg0 * ow1[j];
        ws[L_OW1 + 32 + j] = KT * sg1 * ow1[32 + j];
    }

    if (lane == 0) {
        float cw0 = 0.f, cw1 = 0.f, co3 = 0.f;
        for (int k = 0; k < 32; ++k) {
            cw0 += pw3[k * 2]; cw1 += pw3[k * 2 + 1]; co3 += ow3[k];
        }
        ws[L_SC + 0] = 0.5f * (pb3[0] + cw0);
        ws[L_SC + 1] = 0.5f * (pb3[1] + cw1);
        ws[L_SC + 2] = ob3[0] + co3;
        ws[L_SC + 3] = 0.f;

        // fixed circuit matrix U
        cplx U[16];
        for (int i = 0; i < 16; ++i) U[i] = {0.f, 0.f};
        U[0].re = U[5].re = U[10].re = U[15].re = 1.f;
        for (int l = 0; l < 2; ++l) {
            cplx g[2][4];
            for (int w = 0; w < 2; ++w) {
                float a = qw[l * 6 + w * 3 + 0];
                float b = qw[l * 6 + w * 3 + 1];
                float c = qw[l * 6 + w * 3 + 2];
                float sa, ca, sb, cb, sc, cc;
                __sincosf(0.5f * a, &sa, &ca);
                __sincosf(0.5f * b, &sb, &cb);
                __sincosf(0.5f * c, &sc, &cc);
                cplx RX[4] = {{ca, 0.f}, {0.f, -sa}, {0.f, -sa}, {ca, 0.f}};
                cplx RY[4] = {{cb, 0.f}, {-sb, 0.f}, {sb, 0.f}, {cb, 0.f}};
                cplx RZ[4] = {{cc, -sc}, {0.f, 0.f}, {0.f, 0.f}, {cc, sc}};
                cplx T[4];
                for (int i2 = 0; i2 < 2; ++i2)
                    for (int j2 = 0; j2 < 2; ++j2) {
                        cplx acc = {0.f, 0.f};
                        for (int k2 = 0; k2 < 2; ++k2)
                            acc = cadd(acc, cmul(RY[i2 * 2 + k2], RX[k2 * 2 + j2]));
                        T[i2 * 2 + j2] = acc;
                    }
                for (int i2 = 0; i2 < 2; ++i2)
                    for (int j2 = 0; j2 < 2; ++j2) {
                        cplx acc = {0.f, 0.f};
                        for (int k2 = 0; k2 < 2; ++k2)
                            acc = cadd(acc, cmul(RZ[i2 * 2 + k2], T[k2 * 2 + j2]));
                        g[w][i2 * 2 + j2] = acc;
                    }
            }
            cplx L[16];
            for (int i4 = 0; i4 < 4; ++i4) {
                int si = (i4 == 2) ? 3 : (i4 == 3) ? 2 : i4;
                for (int j4 = 0; j4 < 4; ++j4)
                    L[i4 * 4 + j4] = cmul(g[1][(si & 1) * 2 + (j4 & 1)],
                                          g[0][(si >> 1) * 2 + (j4 >> 1)]);
            }
            cplx Un[16];
            for (int i4 = 0; i4 < 4; ++i4)
                for (int j4 = 0; j4 < 4; ++j4) {
                    cplx acc = {0.f, 0.f};
                    for (int k4 = 0; k4 < 4; ++k4)
                        acc = cadd(acc, cmul(L[i4 * 4 + k4], U[k4 * 4 + j4]));
                    Un[i4 * 4 + j4] = acc;
                }
            for (int i = 0; i < 16; ++i) U[i] = Un[i];
        }
        for (int i = 0; i < 16; ++i) { ws[L_U + i] = U[i].re; ws[L_U + 16 + i] = U[i].im; }
    }
}

// ---------------------------------------------------------------------------
// Main: block = 256 = 4 waves; wave = 8 tiles (4 float2 pairs) x 16 samples
// = 128 samples/wave, 512 samples/block.
// ---------------------------------------------------------------------------
#define NT 8
__global__ __launch_bounds__(256) void qcpinn_main(
    const float* __restrict__ x, const float* __restrict__ ws,
    float* __restrict__ out, int N)
{
    __shared__ float lds[L_TOT];
    {
        const float4* src = (const float4*)ws;
        float4* dst = (float4*)lds;
        for (int i = threadIdx.x; i < L_TOT / 4; i += 256) dst[i] = src[i];
    }
    __syncthreads();

    const int lane = threadIdx.x & 63;
    const int wid  = threadIdx.x >> 6;
    const int s    = lane & 15;
    const int g    = lane >> 4;
    const int base = (blockIdx.x * 4 + wid) * (NT * 16);

    const Frag* frag = (const Frag*)(lds + L_FRAG);

    float xv[NT];
    #pragma unroll
    for (int t = 0; t < NT; ++t) {
        int idx = base + t * 16 + s;
        xv[t] = (idx < N) ? x[idx] : 0.f;
    }

    f32x4 w1a = *(const f32x4*)(lds + L_W1 + g * 8);
    f32x4 w1b = *(const f32x4*)(lds + L_W1 + g * 8 + 4);
    f32x4 b1a = *(const f32x4*)(lds + L_B1 + g * 8);
    f32x4 b1b = *(const f32x4*)(lds + L_B1 + g * 8 + 4);
    Frag A0h = frag[0 * 64 + lane], A0l = frag[1 * 64 + lane];
    Frag A1h = frag[2 * 64 + lane], A1l = frag[3 * 64 + lane];
    f32x4 bh2a = *(const f32x4*)(lds + L_BH2 + g * 4);
    f32x4 bh2b = *(const f32x4*)(lds + L_BH2 + 16 + g * 4);
    f32x4 w3a = *(const f32x4*)(lds + L_W3 + g * 8);
    f32x4 w3b = *(const f32x4*)(lds + L_W3 + g * 8 + 4);
    f32x4 w3c = *(const f32x4*)(lds + L_W3 + 32 + g * 8);
    f32x4 w3d = *(const f32x4*)(lds + L_W3 + 32 + g * 8 + 4);
    f32x4 Ure = *(const f32x4*)(lds + L_U + g * 4);
    f32x4 Uim = *(const f32x4*)(lds + L_U + 16 + g * 4);
    const float qb0 = lds[L_SC + 0], qb1 = lds[L_SC + 1], bo = lds[L_SC + 2];
    f32x4 oa   = *(const f32x4*)(lds + L_OW1 + g * 8);
    f32x4 oa2  = *(const f32x4*)(lds + L_OW1 + g * 8 + 4);
    f32x4 obv  = *(const f32x4*)(lds + L_OW1 + 32 + g * 8);
    f32x4 ob2v = *(const f32x4*)(lds + L_OW1 + 32 + g * 8 + 4);
    f32x4 obb  = *(const f32x4*)(lds + L_OB1 + g * 8);
    f32x4 obb2 = *(const f32x4*)(lds + L_OB1 + g * 8 + 4);
    Frag P0h = frag[4 * 64 + lane], P0l = frag[5 * 64 + lane];
    Frag P1h = frag[6 * 64 + lane], P1l = frag[7 * 64 + lane];
    f32x4 bpa = *(const f32x4*)(lds + L_BH2P + g * 4);
    f32x4 bpb = *(const f32x4*)(lds + L_BH2P + 16 + g * 4);
    f32x4 w3o0 = *(const f32x4*)(lds + L_OW3 + g * 4);
    f32x4 w3o1 = *(const f32x4*)(lds + L_OW3 + 16 + g * 4);

    float uo[NT];
    #pragma unroll
    for (int p = 0; p < NT / 2; ++p) {
        f32x2 xv2 = (f32x2){xv[2 * p], xv[2 * p + 1]};

        // pre layer 1: r1 = sig(KT*(w1*x+b1)) -- packed over tile pair
        f32x2 r1v[8];
        #pragma unroll
        for (int j = 0; j < 4; ++j) {
            r1v[j]     = sig2(fma2(xv2, splat2(w1a[j]), splat2(b1a[j])));
            r1v[4 + j] = sig2(fma2(xv2, splat2(w1b[j]), splat2(b1b[j])));
        }
        Frag Be, Bo;
        #pragma unroll
        for (int w = 0; w < 4; ++w) {
            Be.u[w] = pk_bf16(r1v[2 * w].x, r1v[2 * w + 1].x);
            Bo.u[w] = pk_bf16(r1v[2 * w].y, r1v[2 * w + 1].y);
        }

        // pre layer 2 (MFMA, per tile)
        f32x4 C0e = bh2a, C1e = bh2b, C0o = bh2a, C1o = bh2b;
        C0e = __builtin_amdgcn_mfma_f32_16x16x32_bf16(A0h.s, Be.s, C0e, 0, 0, 0);
        C0e = __builtin_amdgcn_mfma_f32_16x16x32_bf16(A0l.s, Be.s, C0e, 0, 0, 0);
        C1e = __builtin_amdgcn_mfma_f32_16x16x32_bf16(A1h.s, Be.s, C1e, 0, 0, 0);
        C1e = __builtin_amdgcn_mfma_f32_16x16x32_bf16(A1l.s, Be.s, C1e, 0, 0, 0);
        C0o = __builtin_amdgcn_mfma_f32_16x16x32_bf16(A0h.s, Bo.s, C0o, 0, 0, 0);
        C0o = __builtin_amdgcn_mfma_f32_16x16x32_bf16(A0l.s, Bo.s, C0o, 0, 0, 0);
        C1o = __builtin_amdgcn_mfma_f32_16x16x32_bf16(A1h.s, Bo.s, C1o, 0, 0, 0);
        C1o = __builtin_amdgcn_mfma_f32_16x16x32_bf16(A1l.s, Bo.s, C1o, 0, 0, 0);

        f32x2 r2v[8];
        #pragma unroll
        for (int i = 0; i < 4; ++i) {
            r2v[i]     = sig2((f32x2){C0e[i], C0o[i]});
            r2v[4 + i] = sig2((f32x2){C1e[i], C1o[i]});
        }

        // pre layer 3 (32->2) partial dots, packed
        f32x2 q0 = r2v[0] * splat2(w3a[0]);
        f32x2 q1 = r2v[0] * splat2(w3a[1]);
        q0 = fma2(r2v[1], splat2(w3a[2]), q0); q1 = fma2(r2v[1], splat2(w3a[3]), q1);
        q0 = fma2(r2v[2], splat2(w3b[0]), q0); q1 = fma2(r2v[2], splat2(w3b[1]), q1);
        q0 = fma2(r2v[3], splat2(w3b[2]), q0); q1 = fma2(r2v[3], splat2(w3b[3]), q1);
        q0 = fma2(r2v[4], splat2(w3c[0]), q0); q1 = fma2(r2v[4], splat2(w3c[1]), q1);
        q0 = fma2(r2v[5], splat2(w3c[2]), q0); q1 = fma2(r2v[5], splat2(w3c[3]), q1);
        q0 = fma2(r2v[6], splat2(w3d[0]), q0); q1 = fma2(r2v[6], splat2(w3d[1]), q1);
        q0 = fma2(r2v[7], splat2(w3d[2]), q0); q1 = fma2(r2v[7], splat2(w3d[3]), q1);
        q0 += shfl2(q0, 16); q0 += shfl2(q0, 32); q0 += splat2(qb0);
        q1 += shfl2(q1, 16); q1 += shfl2(q1, 32); q1 += splat2(qb1);

        // quantum: p = |(U e)_g|^2, group-split row (q already halved).
        // sincos via scalar temps (vector elements are not addressable).
        float s0x, c0x, s0y, c0y, s1x, c1x, s1y, c1y;
        __sincosf(q0.x, &s0x, &c0x); __sincosf(q0.y, &s0y, &c0y);
        __sincosf(q1.x, &s1x, &c1x); __sincosf(q1.y, &s1y, &c1y);
        f32x2 s0 = (f32x2){s0x, s0y}, c0 = (f32x2){c0x, c0y};
        f32x2 s1 = (f32x2){s1x, s1y}, c1 = (f32x2){c1x, c1y};
        f32x2 e0 = c0 * c1, e1 = c0 * s1, e2 = s0 * c1, e3 = s0 * s1;
        f32x2 re = fma2(splat2(Ure[0]), e0, fma2(splat2(Ure[1]), e1,
                   fma2(splat2(Ure[2]), e2, splat2(Ure[3]) * e3)));
        f32x2 im = fma2(splat2(Uim[0]), e0, fma2(splat2(Uim[1]), e1,
                   fma2(splat2(Uim[2]), e2, splat2(Uim[3]) * e3)));
        f32x2 pq = fma2(re, re, im * im);

        // z-butterfly (signs baked into ow1)
        f32x2 pr = shfl2(pq, 16);
        f32x2 sm = pq + pr, df = pq - pr;
        f32x2 z0 = sm - shfl2(sm, 32);
        f32x2 z1 = df + shfl2(df, 32);

        // post layer 1: 2 -> 32, packed
        f32x2 r3v[8];
        #pragma unroll
        for (int j = 0; j < 4; ++j) {
            r3v[j]     = sig2(fma2(z0, splat2(oa[j]),
                              fma2(z1, splat2(obv[j]),  splat2(obb[j]))));
            r3v[4 + j] = sig2(fma2(z0, splat2(oa2[j]),
                              fma2(z1, splat2(ob2v[j]), splat2(obb2[j]))));
        }
        Frag B2e, B2o;
        #pragma unroll
        for (int w = 0; w < 4; ++w) {
            B2e.u[w] = pk_bf16(r3v[2 * w].x, r3v[2 * w + 1].x);
            B2o.u[w] = pk_bf16(r3v[2 * w].y, r3v[2 * w + 1].y);
        }

        // post layer 2 (MFMA) + layer 3 partial dot
        f32x4 D0e = bpa, D1e = bpb, D0o = bpa, D1o = bpb;
        D0e = __builtin_amdgcn_mfma_f32_16x16x32_bf16(P0h.s, B2e.s, D0e, 0, 0, 0);
        D0e = __builtin_amdgcn_mfma_f32_16x16x32_bf16(P0l.s, B2e.s, D0e, 0, 0, 0);
        D1e = __builtin_amdgcn_mfma_f32_16x16x32_bf16(P1h.s, B2e.s, D1e, 0, 0, 0);
        D1e = __builtin_amdgcn_mfma_f32_16x16x32_bf16(P1l.s, B2e.s, D1e, 0, 0, 0);
        D0o = __builtin_amdgcn_mfma_f32_16x16x32_bf16(P0h.s, B2o.s, D0o, 0, 0, 0);
        D0o = __builtin_amdgcn_mfma_f32_16x16x32_bf16(P0l.s, B2o.s, D0o, 0, 0, 0);
        D1o = __builtin_amdgcn_mfma_f32_16x16x32_bf16(P1h.s, B2o.s, D1o, 0, 0, 0);
        D1o = __builtin_amdgcn_mfma_f32_16x16x32_bf16(P1l.s, B2o.s, D1o, 0, 0, 0);

        f32x2 u = splat2(0.f);
        #pragma unroll
        for (int i = 0; i < 4; ++i) {
            u = fma2(sig2((f32x2){D0e[i], D0o[i]}), splat2(w3o0[i]), u);
            u = fma2(sig2((f32x2){D1e[i], D1o[i]}), splat2(w3o1[i]), u);
        }
        u += shfl2(u, 16);
        u += shfl2(u, 32);
        uo[2 * p]     = u.x;
        uo[2 * p + 1] = u.y;
    }

    // coalesced stores: lane (g,s) -> samples base+lane and base+64+lane
    float ua = (g & 1) ? uo[1] : uo[0];
    float ub = (g & 1) ? uo[3] : uo[2];
    float us0 = ((g & 2) ? ub : ua) + bo;
    float uc = (g & 1) ? uo[5] : uo[4];
    float ud = (g & 1) ? uo[7] : uo[6];
    float us1 = ((g & 2) ? ud : uc) + bo;
    int o0 = base + lane, o1 = base + 64 + lane;
    if (o0 < N) out[o0] = us0;
    if (o1 < N) out[o1] = us1;
}

extern "C" void kernel_launch(void* const* d_in, const int* in_sizes, int n_in,
                              void* d_out, int out_size, void* d_ws, size_t ws_size,
                              hipStream_t stream) {
    const float* x   = (const float*)d_in[0];
    const float* pw1 = (const float*)d_in[1];
    const float* pb1 = (const float*)d_in[2];
    const float* pw2 = (const float*)d_in[3];
    const float* pb2 = (const float*)d_in[4];
    const float* pw3 = (const float*)d_in[5];
    const float* pb3 = (const float*)d_in[6];
    const float* qw  = (const float*)d_in[7];
    const float* ow1 = (const float*)d_in[8];
    const float* ob1 = (const float*)d_in[9];
    const float* ow2 = (const float*)d_in[10];
    const float* ob2 = (const float*)d_in[11];
    const float* ow3 = (const float*)d_in[12];
    const float* ob3 = (const float*)d_in[13];
    float* out = (float*)d_out;
    float* ws  = (float*)d_ws;

    const int N = in_sizes[0];

    qcpinn_setup<<<1, 64, 0, stream>>>(pw1, pb1, pw2, pb2, pw3, pb3, qw,
                                       ow1, ob1, ow2, ob2, ow3, ob3, ws);

    const int grid = (N + 511) / 512;   // 512 samples per block
    qcpinn_main<<<grid, 256, 0, stream>>>(x, ws, out, N);
}